// Round 4
// baseline (760.881 us; speedup 1.0000x reference)
//
#include <hip/hip_runtime.h>
#include <hip/hip_bf16.h>
#include <math.h>

#define B_  4
#define S_  2048
#define D_  2048
#define H_  16
#define G_  4
#define HD_ 128

typedef __attribute__((ext_vector_type(8))) short short8;
typedef __attribute__((ext_vector_type(4))) float floatx4;
typedef __attribute__((ext_vector_type(4))) int int4v;

__device__ __forceinline__ short f2bf(float f) {
    unsigned u = __float_as_uint(f);
    unsigned r = (u + 0x7fff + ((u >> 16) & 1)) >> 16;
    return (short)r;
}
__device__ __forceinline__ float b2f(short s) {
    return __uint_as_float(((unsigned)(unsigned short)s) << 16);
}
// pack two floats to bf16x2, round-half-up (cheap; used for P)
__device__ __forceinline__ unsigned pk2(float a, float b) {
    unsigned ua = (__float_as_uint(a) + 0x8000u) >> 16;
    unsigned ub = (__float_as_uint(b) + 0x8000u) & 0xffff0000u;
    return ua | ub;
}
// pack two floats to bf16x2, RNE (outputs)
__device__ __forceinline__ unsigned pkr(float a, float b) {
    return (unsigned)(unsigned short)f2bf(a) |
           ((unsigned)(unsigned short)f2bf(b) << 16);
}

#define GLL16(gp, lp) __builtin_amdgcn_global_load_lds( \
    (const __attribute__((address_space(1))) void*)(gp), \
    (__attribute__((address_space(3))) void*)(lp), 16, 0, 0)

// ---------------------------------------------------------------------------
// fp32 -> bf16 convert (8 elems/thread)
// ---------------------------------------------------------------------------
__global__ void cvt_bf16_kernel(const float* __restrict__ in,
                                short* __restrict__ out, int n8)
{
    int t = blockIdx.x * 256 + threadIdx.x;
    if (t >= n8) return;
    const float4* p = (const float4*)in + (size_t)t * 2;
    float4 a = p[0], b = p[1];
    short8 r;
    r[0] = f2bf(a.x); r[1] = f2bf(a.y); r[2] = f2bf(a.z); r[3] = f2bf(a.w);
    r[4] = f2bf(b.x); r[5] = f2bf(b.y); r[6] = f2bf(b.z); r[7] = f2bf(b.w);
    ((short8*)out)[t] = r;
}

// ---------------------------------------------------------------------------
// W[K][N] fp32 -> Wt[N][K] bf16, 32x32 LDS tiles
// ---------------------------------------------------------------------------
__global__ __launch_bounds__(256) void tr_bf16_kernel(
    const float* __restrict__ in, short* __restrict__ out, int K, int N)
{
    __shared__ float T[32][33];
    int n0 = blockIdx.x * 32, k0 = blockIdx.y * 32;
    int tx = threadIdx.x & 31, ty = threadIdx.x >> 5;
#pragma unroll
    for (int i = 0; i < 4; ++i)
        T[ty + i * 8][tx] = in[(size_t)(k0 + ty + i * 8) * N + n0 + tx];
    __syncthreads();
#pragma unroll
    for (int i = 0; i < 4; ++i)
        out[(size_t)(n0 + ty + i * 8) * K + k0 + tx] = f2bf(T[tx][ty + i * 8]);
}

// ---------------------------------------------------------------------------
// Merged QKV GEMM: [M,3072] = xb[M,2048] @ Wt[3072,2048]^T (+bias).
// n<2048 -> qb8 (b,s,h,hd); n<2560 -> kb8 (b,s,g,hd); else vt8 TRANSPOSED
// (b,g,dv,s') with the key axis PERMUTED within 32-key groups
// (s=16b+4c+d -> s'=8c+4b+d) so attention's PV B-operand is lane-local.
// ---------------------------------------------------------------------------
__global__ __launch_bounds__(256) void gemm_qkv(
    const short* __restrict__ A, const short* __restrict__ Bt,
    const float* __restrict__ bq, const float* __restrict__ bk,
    const float* __restrict__ bv, short* __restrict__ qout,
    short* __restrict__ kout, short* __restrict__ vout, int M, int N, int K)
{
    __shared__ short As[128 * 32];
    __shared__ short Bs[128 * 32];
    const int tid = threadIdx.x;
    const int w = tid >> 6, l15 = tid & 15, quad = (tid & 63) >> 4;
    const int wm = w >> 1, wn = w & 1;
    const int m0 = blockIdx.y * 128, n0 = blockIdx.x * 128;

    floatx4 acc[4][4];
#pragma unroll
    for (int i = 0; i < 4; ++i)
#pragma unroll
        for (int j = 0; j < 4; ++j) acc[i][j] = (floatx4){0.f, 0.f, 0.f, 0.f};

    const int arow = tid >> 2, akc = tid & 3;
    const short* Ag0 = A + (size_t)(m0 + arow) * K + akc * 8;
    const short* Ag1 = A + (size_t)(m0 + 64 + arow) * K + akc * 8;
    const short* Bg0 = Bt + (size_t)(n0 + arow) * K + akc * 8;
    const short* Bg1 = Bt + (size_t)(n0 + 64 + arow) * K + akc * 8;
    short* AsW0 = As + (w * 64) * 8;
    short* AsW1 = As + (256 + w * 64) * 8;
    short* BsW0 = Bs + (w * 64) * 8;
    short* BsW1 = Bs + (256 + w * 64) * 8;

    for (int k0 = 0; k0 < K; k0 += 32) {
        GLL16(Ag0 + k0, AsW0);
        GLL16(Ag1 + k0, AsW1);
        GLL16(Bg0 + k0, BsW0);
        GLL16(Bg1 + k0, BsW1);
        __syncthreads();
        short8 af[4], bfr[4];
#pragma unroll
        for (int mt = 0; mt < 4; ++mt)
            af[mt] = *(const short8*)(As + (wm * 64 + mt * 16 + l15) * 32 + quad * 8);
#pragma unroll
        for (int nt = 0; nt < 4; ++nt)
            bfr[nt] = *(const short8*)(Bs + (wn * 64 + nt * 16 + l15) * 32 + quad * 8);
#pragma unroll
        for (int mt = 0; mt < 4; ++mt)
#pragma unroll
            for (int nt = 0; nt < 4; ++nt)
                acc[mt][nt] = __builtin_amdgcn_mfma_f32_16x16x32_bf16(
                    af[mt], bfr[nt], acc[mt][nt], 0, 0, 0);
        __syncthreads();
    }

#pragma unroll
    for (int nt = 0; nt < 4; ++nt) {
        int gcol = n0 + wn * 64 + nt * 16 + l15;
        float bvv = (gcol < 2048) ? bq[gcol]
                  : (gcol < 2560) ? bk[gcol - 2048] : bv[gcol - 2560];
#pragma unroll
        for (int mt = 0; mt < 4; ++mt) {
            int grow = m0 + wm * 64 + mt * 16 + quad * 4;
            floatx4 v = acc[mt][nt];
            if (n0 < 2048) {
#pragma unroll
                for (int r = 0; r < 4; ++r)
                    qout[(size_t)(grow + r) * 2048 + gcol] = f2bf(v[r] + bvv);
            } else if (n0 < 2560) {
                int c = gcol - 2048;
#pragma unroll
                for (int r = 0; r < 4; ++r)
                    kout[(size_t)(grow + r) * 512 + c] = f2bf(v[r] + bvv);
            } else {
                int c = gcol - 2560, gg = c >> 7, dv = c & 127;
                int bb = grow >> 11, s = grow & 2047;
                // permuted key position (s&3==0 here)
                int sp = (s & ~31) | ((s & 12) << 1) | ((s & 16) >> 2);
                uint2 pk;
                pk.x = pkr(v[0] + bvv, v[1] + bvv);
                pk.y = pkr(v[2] + bvv, v[3] + bvv);
                *(uint2*)&vout[(((size_t)bb * G_ + gg) * HD_ + dv) * S_ + sp] = pk;
            }
        }
    }
}

// ---------------------------------------------------------------------------
// bf16 MFMA GEMM (O-projection): C[M,N] fp32 = A[M,K] @ Bt[N,K]^T + bias
// ---------------------------------------------------------------------------
__global__ __launch_bounds__(256) void gemm_nt_f32(
    const short* __restrict__ A, const short* __restrict__ Bt,
    const float* __restrict__ bias, float* __restrict__ C,
    int M, int N, int K)
{
    __shared__ short As[128 * 32];
    __shared__ short Bs[128 * 32];
    const int tid = threadIdx.x;
    const int w = tid >> 6, l15 = tid & 15, quad = (tid & 63) >> 4;
    const int wm = w >> 1, wn = w & 1;
    const int m0 = blockIdx.y * 128, n0 = blockIdx.x * 128;

    floatx4 acc[4][4];
#pragma unroll
    for (int i = 0; i < 4; ++i)
#pragma unroll
        for (int j = 0; j < 4; ++j) acc[i][j] = (floatx4){0.f, 0.f, 0.f, 0.f};

    const int arow = tid >> 2, akc = tid & 3;
    const short* Ag0 = A + (size_t)(m0 + arow) * K + akc * 8;
    const short* Ag1 = A + (size_t)(m0 + 64 + arow) * K + akc * 8;
    const short* Bg0 = Bt + (size_t)(n0 + arow) * K + akc * 8;
    const short* Bg1 = Bt + (size_t)(n0 + 64 + arow) * K + akc * 8;
    short* AsW0 = As + (w * 64) * 8;
    short* AsW1 = As + (256 + w * 64) * 8;
    short* BsW0 = Bs + (w * 64) * 8;
    short* BsW1 = Bs + (256 + w * 64) * 8;

    for (int k0 = 0; k0 < K; k0 += 32) {
        GLL16(Ag0 + k0, AsW0);
        GLL16(Ag1 + k0, AsW1);
        GLL16(Bg0 + k0, BsW0);
        GLL16(Bg1 + k0, BsW1);
        __syncthreads();
        short8 af[4], bfr[4];
#pragma unroll
        for (int mt = 0; mt < 4; ++mt)
            af[mt] = *(const short8*)(As + (wm * 64 + mt * 16 + l15) * 32 + quad * 8);
#pragma unroll
        for (int nt = 0; nt < 4; ++nt)
            bfr[nt] = *(const short8*)(Bs + (wn * 64 + nt * 16 + l15) * 32 + quad * 8);
#pragma unroll
        for (int mt = 0; mt < 4; ++mt)
#pragma unroll
            for (int nt = 0; nt < 4; ++nt)
                acc[mt][nt] = __builtin_amdgcn_mfma_f32_16x16x32_bf16(
                    af[mt], bfr[nt], acc[mt][nt], 0, 0, 0);
        __syncthreads();
    }

#pragma unroll
    for (int nt = 0; nt < 4; ++nt) {
        int gcol = n0 + wn * 64 + nt * 16 + l15;
        float bvv = bias[gcol];
#pragma unroll
        for (int mt = 0; mt < 4; ++mt) {
            int grow = m0 + wm * 64 + mt * 16 + quad * 4;
            floatx4 v = acc[mt][nt];
#pragma unroll
            for (int r = 0; r < 4; ++r)
                C[(size_t)(grow + r) * N + gcol] = v[r] + bvv;
        }
    }
}

// ---------------------------------------------------------------------------
// RoPE in-place on bf16 (B,S,nh,HD); fp32 trig (err 1e-4 << bf16 ulp)
// ---------------------------------------------------------------------------
__global__ void rope_bf16_kernel(short* __restrict__ p, int nh, float scale,
                                 int total)
{
    int gid = blockIdx.x * 256 + threadIdx.x;
    if (gid >= total) return;
    int i = gid & 63;
    int rest = gid >> 6;
    int head = rest % nh;
    int rest2 = rest / nh;
    int s = rest2 & (S_ - 1);
    int b = rest2 >> 11;
    size_t base = (((size_t)b * S_ + s) * nh + head) * HD_;
    float inv = __expf((float)i * -0.14391156509f);   // ln(1e4)/64
    float ang = (float)s * inv;
    float sn, cs;
    sincosf(ang, &sn, &cs);
    float t1 = b2f(p[base + i]), t2 = b2f(p[base + 64 + i]);
    p[base + i]      = f2bf((t1 * cs - t2 * sn) * scale);
    p[base + 64 + i] = f2bf((t2 * cs + t1 * sn) * scale);
}

// ---------------------------------------------------------------------------
// MFMA flash attention v3: S^T design, P entirely in registers.
// Block = 128 q-rows of one (b,h); wave = 32 q-rows; K-tile = 64 keys.
// S^T = K·Q^T (lane-local softmax state). O^T = V^T·P^T where V^T's key
// axis is pre-permuted (by gemm_qkv) so the PV B-fragment is exactly the
// lane's own packed exp(sa) registers — no LDS round-trip for P.
// LDS = 32KB (Ks+Vs); __launch_bounds__(256,4) caps VGPR at 128 -> 4 w/SIMD.
// ---------------------------------------------------------------------------
__global__ __launch_bounds__(256, 4) void attn_mfma3(
    short* __restrict__ qb, const short* __restrict__ kb,
    const short* __restrict__ vt)
{
    __shared__ short Ks[64 * 128];      // [key][16B-chunk], chunk ^= key&7
    __shared__ short Vs[128 * 64];      // [dv][16B-chunk],  chunk ^= dv&7

    const int tid = threadIdx.x;
    const int w = tid >> 6, lane = tid & 63, l15 = lane & 15, quad = lane >> 4;
    const int qi = 15 - (int)blockIdx.x;          // heavy blocks first
    const int q0 = qi * 128;
    const int bh = blockIdx.y, b = bh >> 4, h = bh & 15, g = h >> 2;

    // Q fragments: rows q0 + w*32 + qs*16 + l15, d = quad*8 + 32c
    const short* qp = qb + ((((size_t)b * S_) + q0 + w * 32 + l15) * H_ + h) * HD_
                      + quad * 8;
    short8 qf[2][4];
#pragma unroll
    for (int qs = 0; qs < 2; ++qs)
#pragma unroll
        for (int c = 0; c < 4; ++c)
            qf[qs][c] = *(const short8*)(qp + qs * 16 * (H_ * HD_) + c * 32);

    floatx4 ot[2][8];
#pragma unroll
    for (int qs = 0; qs < 2; ++qs)
#pragma unroll
        for (int s = 0; s < 8; ++s) ot[qs][s] = (floatx4){0.f, 0.f, 0.f, 0.f};
    float m_i[2] = {-1e30f, -1e30f}, l_i[2] = {0.f, 0.f};

    // staging maps
    const int kkey = tid >> 4, kch = tid & 15;
    const int ksrc = kch ^ (kkey & 7);
    const short* kgb = kb + (((size_t)b * S_) * G_ + g) * HD_ + ksrc * 8;
    const int vdv = tid >> 3, vch = tid & 7;
    const int vsrc = vch ^ (vdv & 7);
    const short* vgb = vt + (((size_t)(b * G_ + g)) * HD_ + vdv) * (size_t)S_
                       + vsrc * 8;
    const int sw = l15 & 7;

    const int nkt = 2 * (qi + 1);
    for (int kt = 0; kt < nkt; ++kt) {
        __syncthreads();
        const short* kg = kgb + (size_t)(kt * 64) * (G_ * HD_);
        const short* vg = vgb + kt * 64;
#pragma unroll
        for (int i = 0; i < 4; ++i)
            GLL16(kg + (size_t)(kkey + 16 * i) * (G_ * HD_),
                  Ks + (w * 64 + 256 * i) * 8);
#pragma unroll
        for (int i = 0; i < 4; ++i)
            GLL16(vg + (size_t)(32 * i) * S_, Vs + (w * 64 + 256 * i) * 8);
        __syncthreads();

        const int kbase = kt * 64;
        int4v pf[2][2];   // [qs][kc] packed bf16 P, lane-local

#pragma unroll
        for (int qs = 0; qs < 2; ++qs) {
            // ---- S^T: rows = keys ks*16+quad*4+r, col = own query (l15)
            floatx4 sa[4];
#pragma unroll
            for (int ks = 0; ks < 4; ++ks) sa[ks] = (floatx4){0.f, 0.f, 0.f, 0.f};
#pragma unroll
            for (int c = 0; c < 4; ++c)
#pragma unroll
                for (int ks = 0; ks < 4; ++ks) {
                    short8 kf = *(const short8*)(Ks +
                        ((l15 + 16 * ks) * 16 + ((c * 4 + quad) ^ sw)) * 8);
                    sa[ks] = __builtin_amdgcn_mfma_f32_16x16x32_bf16(
                        kf, qf[qs][c], sa[ks], 0, 0, 0);
                }

            const int qrow = q0 + w * 32 + qs * 16 + l15;
            if (kbase + 63 > q0 + w * 32 + qs * 16) {   // near diagonal only
#pragma unroll
                for (int ks = 0; ks < 4; ++ks)
#pragma unroll
                    for (int r = 0; r < 4; ++r)
                        if (kbase + ks * 16 + quad * 4 + r > qrow)
                            sa[ks][r] = -1e30f;
            }
            // ---- lane-local online softmax (16 scores + 2 shfl)
            float mx = -1e30f;
#pragma unroll
            for (int ks = 0; ks < 4; ++ks)
#pragma unroll
                for (int r = 0; r < 4; ++r) mx = fmaxf(mx, sa[ks][r]);
            mx = fmaxf(mx, __shfl_xor(mx, 16));
            mx = fmaxf(mx, __shfl_xor(mx, 32));
            float mn = fmaxf(m_i[qs], mx);
            float al = __expf(m_i[qs] - mn);
            m_i[qs] = mn;
            float sum = 0.f;
#pragma unroll
            for (int ks = 0; ks < 4; ++ks)
#pragma unroll
                for (int r = 0; r < 4; ++r) {
                    float p = __expf(sa[ks][r] - mn);
                    sa[ks][r] = p;
                    sum += p;
                }
            sum += __shfl_xor(sum, 16);
            sum += __shfl_xor(sum, 32);
            l_i[qs] = l_i[qs] * al + sum;
#pragma unroll
            for (int s = 0; s < 8; ++s) {
                floatx4 o = ot[qs][s];
                o[0] *= al; o[1] *= al; o[2] *= al; o[3] *= al;
                ot[qs][s] = o;
            }
            // ---- pack P (B-operand for permuted-key V): all lane-local
            pf[qs][0] = (int4v){(int)pk2(sa[0][0], sa[0][1]),
                                (int)pk2(sa[0][2], sa[0][3]),
                                (int)pk2(sa[1][0], sa[1][1]),
                                (int)pk2(sa[1][2], sa[1][3])};
            pf[qs][1] = (int4v){(int)pk2(sa[2][0], sa[2][1]),
                                (int)pk2(sa[2][2], sa[2][3]),
                                (int)pk2(sa[3][0], sa[3][1]),
                                (int)pk2(sa[3][2], sa[3][3])};
        }

        // ---- O^T += V^T · P^T  (V-frags shared across both q-subtiles)
#pragma unroll
        for (int kc = 0; kc < 2; ++kc) {
            short8 pf0 = __builtin_bit_cast(short8, pf[0][kc]);
            short8 pf1 = __builtin_bit_cast(short8, pf[1][kc]);
#pragma unroll
            for (int s = 0; s < 8; ++s) {
                short8 vf = *(const short8*)(Vs +
                    ((l15 + 16 * s) * 8 + ((kc * 4 + quad) ^ sw)) * 8);
                ot[0][s] = __builtin_amdgcn_mfma_f32_16x16x32_bf16(
                    vf, pf0, ot[0][s], 0, 0, 0);
                ot[1][s] = __builtin_amdgcn_mfma_f32_16x16x32_bf16(
                    vf, pf1, ot[1][s], 0, 0, 0);
            }
        }
    }

    // ---- epilogue: normalize (lane-local l), write bf16 in-place
#pragma unroll
    for (int qs = 0; qs < 2; ++qs) {
        float inv = 1.f / l_i[qs];
        size_t base = ((((size_t)b * S_) + q0 + w * 32 + qs * 16 + l15) * H_ + h)
                      * HD_;
#pragma unroll
        for (int s = 0; s < 8; ++s) {
            uint2 pkv;
            pkv.x = pkr(ot[qs][s][0] * inv, ot[qs][s][1] * inv);
            pkv.y = pkr(ot[qs][s][2] * inv, ot[qs][s][3] * inv);
            *(uint2*)&qb[base + s * 16 + quad * 4] = pkv;
        }
    }
}

// ---------------------------------------------------------------------------
extern "C" void kernel_launch(void* const* d_in, const int* in_sizes, int n_in,
                              void* d_out, int out_size, void* d_ws, size_t ws_size,
                              hipStream_t stream)
{
    const float* x  = (const float*)d_in[0];
    const float* Wq = (const float*)d_in[1];
    const float* bq = (const float*)d_in[2];
    const float* Wk = (const float*)d_in[3];
    const float* bk = (const float*)d_in[4];
    const float* Wv = (const float*)d_in[5];
    const float* bv = (const float*)d_in[6];
    const float* Wo = (const float*)d_in[7];
    const float* bo = (const float*)d_in[8];
    float* out = (float*)d_out;

    // ws layout (bf16 elements); total 96.5 MB
    short* xb  = (short*)d_ws;        // 16,777,216
    short* Wt  = xb + 16777216;       // 3072*2048 = 6,291,456 (reused for Wo^T)
    short* qb8 = Wt + 6291456;        // 16,777,216 (q -> attn out, in-place)
    short* kb8 = qb8 + 16777216;      // 4,194,304
    short* vt8 = kb8 + 4194304;       // 4,194,304  V^T (b,g,dv,s') key-permuted

    const int M = B_ * S_;
    dim3 blk(256);

    cvt_bf16_kernel<<<8192, blk, 0, stream>>>(x, xb, 16777216 / 8);
    tr_bf16_kernel<<<dim3(64, 64), blk, 0, stream>>>(Wq, Wt, 2048, 2048);
    tr_bf16_kernel<<<dim3(16, 64), blk, 0, stream>>>(Wk, Wt + (size_t)2048 * 2048, 2048, 512);
    tr_bf16_kernel<<<dim3(16, 64), blk, 0, stream>>>(Wv, Wt + (size_t)2560 * 2048, 2048, 512);

    gemm_qkv<<<dim3(24, 64), blk, 0, stream>>>(xb, Wt, bq, bk, bv,
                                               qb8, kb8, vt8, M, 3072, 2048);

    // Wt slot free now -> Wo^T (stream-ordered)
    tr_bf16_kernel<<<dim3(64, 64), blk, 0, stream>>>(Wo, Wt, 2048, 2048);

    const float qscale = 0.08838834764831845f;   // 1/sqrt(128)
    rope_bf16_kernel<<<32768, blk, 0, stream>>>(qb8, H_, qscale, M * H_ * 64);
    rope_bf16_kernel<<<8192,  blk, 0, stream>>>(kb8, G_, 1.0f,   M * G_ * 64);

    attn_mfma3<<<dim3(16, 64), blk, 0, stream>>>(qb8, kb8, vt8);

    gemm_nt_f32<<<dim3(16, 64), blk, 0, stream>>>(qb8, Wt, bo, out, M, 2048, 2048);
}